// Round 16
// baseline (1327.821 us; speedup 1.0000x reference)
//
#include <hip/hip_runtime.h>
#include <stdint.h>

#define VOCAB 32000
#define HID   512
#define G3    1536
#define TT    128
#define BB    32
#define NROW  4096   // TT*BB rows
#define NCB   250    // VOCAB/128 column blocks of the vocab GEMM

typedef __attribute__((ext_vector_type(8))) short short8;
typedef __attribute__((ext_vector_type(4))) short short4v;
typedef __attribute__((ext_vector_type(4))) float f32x4;
typedef __attribute__((ext_vector_type(2))) unsigned long long u64x2;

__device__ __forceinline__ unsigned short f2bf(float f) {
  unsigned int u = __builtin_bit_cast(unsigned int, f);
  u += 0x7fffu + ((u >> 16) & 1u);
  return (unsigned short)(u >> 16);
}
__device__ __forceinline__ float bf2f(unsigned short s) {
  unsigned int u = ((unsigned int)s) << 16;
  return __builtin_bit_cast(float, u);
}
__device__ __forceinline__ void gload16(const void* g, void* l) {
  __builtin_amdgcn_global_load_lds(
      (const __attribute__((address_space(1))) unsigned int*)g,
      (__attribute__((address_space(3))) unsigned int*)l, 16, 0, 0);
}
__device__ __forceinline__ unsigned long long AL64(const unsigned long long* p) {
  return __hip_atomic_load(p, __ATOMIC_RELAXED, __HIP_MEMORY_SCOPE_AGENT);
}
__device__ __forceinline__ unsigned int AL32(const unsigned int* p) {
  return __hip_atomic_load(p, __ATOMIC_RELAXED, __HIP_MEMORY_SCOPE_AGENT);
}
__device__ __forceinline__ void AS64(unsigned long long* p, unsigned long long v) {
  __hip_atomic_store(p, v, __ATOMIC_RELAXED, __HIP_MEMORY_SCOPE_AGENT);
}
__device__ __forceinline__ void AS32(unsigned int* p, unsigned int v) {
  __hip_atomic_store(p, v, __ATOMIC_RELAXED, __HIP_MEMORY_SCOPE_AGENT);
}

// ---------------- f32 [K][N] -> bf16 [N][K] transpose (standalone, encW) -----
__global__ void transpose_bf16_k(const float* __restrict__ src,
                                 unsigned short* __restrict__ dst,
                                 int K, int N) {
  __shared__ float t[64][65];
  int k0 = blockIdx.x * 64, n0 = blockIdx.y * 64;
  int c = threadIdx.x & 15, rr = threadIdx.x >> 4;
#pragma unroll
  for (int i = 0; i < 4; ++i) {
    float4 v = *(const float4*)(src + (size_t)(k0 + rr + 16 * i) * N + n0 + c * 4);
    t[rr + 16 * i][c * 4 + 0] = v.x;
    t[rr + 16 * i][c * 4 + 1] = v.y;
    t[rr + 16 * i][c * 4 + 2] = v.z;
    t[rr + 16 * i][c * 4 + 3] = v.w;
  }
  __syncthreads();
#pragma unroll
  for (int i = 0; i < 4; ++i) {
    short4v o;
#pragma unroll
    for (int j = 0; j < 4; ++j) o[j] = (short)f2bf(t[c * 4 + j][rr + 16 * i]);
    *(short4v*)(dst + (size_t)(n0 + rr + 16 * i) * K + k0 + c * 4) = o;
  }
}

// ---------------- embedding gather -------------------------------------------
__global__ void embed_k(const int* __restrict__ inputs,
                        const float* __restrict__ emb,
                        unsigned short* __restrict__ xb) {
  int r = blockIdx.x;            // r = t*32 + b
  int t = r >> 5, b = r & 31;
  int idx = inputs[b * TT + t];
  const float* src = emb + (size_t)idx * HID;
  unsigned short* dst = xb + (size_t)r * HID;
  int j = threadIdx.x * 4;
  float4 v = *(const float4*)(src + j);
  short4v o;
  o[0] = (short)f2bf(v.x); o[1] = (short)f2bf(v.y);
  o[2] = (short)f2bf(v.z); o[3] = (short)f2bf(v.w);
  *(short4v*)(dst + j) = o;
}

// ---------------- B^T MFMA GEMM, 128x128 tile, BK=64, global_load_lds --------
// XCD-aware block swizzle (grid.x MUST be 32, total blocks % 8 == 0).
// MODE 0: C=f32 +bias. MODE 1: C=bf16 relu(+bias).
// MODE 3: C=bf16 raw logit(+bias) via NON-TEMPORAL stores (streaming output
//         must not evict the IC-resident woutbT) + per-row exp partials.
template<int MODE>
__launch_bounds__(256)
__global__ void gemm_bt(const unsigned short* __restrict__ A,
                        const unsigned short* __restrict__ BT,
                        const float* __restrict__ bias,
                        void* __restrict__ Cv,
                        float* __restrict__ partials,
                        int M, int N, int K) {
  __shared__ unsigned short As[8192];   // 128 rows x 64 k, swizzled, 16 KiB
  __shared__ unsigned short Bs[8192];   // 128 cols x 64 k, swizzled, 16 KiB
  __shared__ float rsum[2][128];
  int tid = threadIdx.x;
  int l = tid & 63;
  int w = tid >> 6;
  int wm = w >> 1, wn = w & 1;

  int nwg = (int)(gridDim.x * gridDim.y);
  int id = (int)(blockIdx.y * gridDim.x + blockIdx.x);
  int nid = (id & 7) * (nwg >> 3) + (id >> 3);
  int bx = nid & 31, by = nid >> 5;     // gridDim.x == 32 by construction
  int row0 = bx * 128;
  int col0 = by * 128;

  int sr = (w << 5) + (l >> 3);                 // + i*8, i=0..3
  int sg = ((l & 7) ^ ((l >> 3) & 7)) << 3;     // short offset in k-window
  const unsigned short* Ag = A  + (size_t)(row0 + sr) * K + sg;
  const unsigned short* Bg = BT + (size_t)(col0 + sr) * K + sg;

  int cA = l & 15, q = l >> 4, x7 = l & 7;
  const char* asp = (const char*)As;
  const char* bsp = (const char*)Bs;

  f32x4 acc[4][4];
#pragma unroll
  for (int m = 0; m < 4; ++m)
#pragma unroll
    for (int n = 0; n < 4; ++n) acc[m][n] = (f32x4){0.f, 0.f, 0.f, 0.f};

  for (int k0 = 0; k0 < K; k0 += 64) {
    if (k0) __syncthreads();               // previous-tile reads complete
#pragma unroll
    for (int i = 0; i < 4; ++i) {
      gload16(Ag + (size_t)(i * 8) * K + k0, As + ((w << 2) + i) * 512);
      gload16(Bg + (size_t)(i * 8) * K + k0, Bs + ((w << 2) + i) * 512);
    }
    __syncthreads();                       // loads landed (vmcnt drained)
#pragma unroll
    for (int kk = 0; kk < 2; ++kk) {
      int sl = (((kk << 2) + q) ^ x7) << 4;   // swizzled 16B slot in row
      short8 af[4], bf[4];
#pragma unroll
      for (int m = 0; m < 4; ++m)
        af[m] = *(const short8*)(asp + (wm * 64 + m * 16 + cA) * 128 + sl);
#pragma unroll
      for (int n = 0; n < 4; ++n)
        bf[n] = *(const short8*)(bsp + (wn * 64 + n * 16 + cA) * 128 + sl);
#pragma unroll
      for (int m = 0; m < 4; ++m)
#pragma unroll
        for (int n = 0; n < 4; ++n)
          acc[m][n] = __builtin_amdgcn_mfma_f32_16x16x32_bf16(af[m], bf[n],
                                                              acc[m][n], 0, 0, 0);
    }
  }

  if (MODE == 0 || MODE == 1) {
#pragma unroll
    for (int m = 0; m < 4; ++m)
#pragma unroll
      for (int n = 0; n < 4; ++n) {
        int col = col0 + wn * 64 + n * 16 + cA;
        float bv = bias[col];
#pragma unroll
        for (int r = 0; r < 4; ++r) {
          int row = row0 + wm * 64 + m * 16 + q * 4 + r;
          float v = acc[m][n][r] + bv;
          if (MODE == 0)
            ((float*)Cv)[(size_t)row * N + col] = v;
          else
            ((unsigned short*)Cv)[(size_t)row * N + col] = f2bf(fmaxf(v, 0.f));
        }
      }
  } else {
    float ps[4][4];
#pragma unroll
    for (int m = 0; m < 4; ++m)
#pragma unroll
      for (int r = 0; r < 4; ++r) ps[m][r] = 0.f;
#pragma unroll
    for (int m = 0; m < 4; ++m)
#pragma unroll
      for (int n = 0; n < 4; ++n) {
        int col = col0 + wn * 64 + n * 16 + cA;
        float bv = bias[col];
#pragma unroll
        for (int r = 0; r < 4; ++r) {
          int row = row0 + wm * 64 + m * 16 + q * 4 + r;
          float lv = acc[m][n][r] + bv;
          float v = __expf(lv);
          __builtin_nontemporal_store(
              f2bf(lv), &((unsigned short*)Cv)[(size_t)row * N + col]);
          ps[m][r] += v;
        }
      }
#pragma unroll
    for (int mask = 1; mask < 16; mask <<= 1)
#pragma unroll
      for (int m = 0; m < 4; ++m)
#pragma unroll
        for (int r = 0; r < 4; ++r)
          ps[m][r] += __shfl_xor(ps[m][r], mask, 64);
    if (cA == 0) {
#pragma unroll
      for (int m = 0; m < 4; ++m)
#pragma unroll
        for (int r = 0; r < 4; ++r)
          rsum[wn][wm * 64 + m * 16 + q * 4 + r] = ps[m][r];
    }
    __syncthreads();
    if (tid < 128)
      partials[(size_t)by * NROW + row0 + tid] = rsum[0][tid] + rsum[1][tid];
  }
}

// ---------------- small GEMM (decoder input projection only) -----------------
__launch_bounds__(256)
__global__ void gemm_small_k(const unsigned short* __restrict__ A,
                             const unsigned short* __restrict__ B,
                             const float* __restrict__ bias,
                             float* __restrict__ C,
                             int M, int N, int K) {
  __shared__ unsigned short As[64][56];
  __shared__ unsigned short Bs[64][56];
  int tid = threadIdx.x;
  int lane = tid & 63;
  int w = tid >> 6;
  int wm = w >> 1, wn = w & 1;
  int row0 = blockIdx.x * 64;
  int n0 = blockIdx.y * 64;
  f32x4 acc[2][2];
#pragma unroll
  for (int a = 0; a < 2; ++a)
#pragma unroll
    for (int c = 0; c < 2; ++c) acc[a][c] = (f32x4){0.f, 0.f, 0.f, 0.f};
  for (int k0 = 0; k0 < K; k0 += 32) {
    {
      int row = tid >> 2;
      int kg = (tid & 3) * 8;
      short8 v = {};
      if (row0 + row < M)
        v = *(const short8*)(A + (size_t)(row0 + row) * K + k0 + kg);
      *(short8*)&As[row][kg] = v;
    }
    {
      int k = tid >> 3;
      int ng = (tid & 7) * 8;
      short8 v = *(const short8*)(B + (size_t)(k0 + k) * N + n0 + ng);
#pragma unroll
      for (int qq = 0; qq < 8; ++qq) Bs[ng + qq][k] = (unsigned short)v[qq];
    }
    __syncthreads();
    int kb = (lane >> 4) * 8;
    short8 af0 = *(const short8*)&As[wm * 32 + (lane & 15)][kb];
    short8 af1 = *(const short8*)&As[wm * 32 + 16 + (lane & 15)][kb];
    short8 bf0 = *(const short8*)&Bs[wn * 32 + (lane & 15)][kb];
    short8 bf1 = *(const short8*)&Bs[wn * 32 + 16 + (lane & 15)][kb];
    acc[0][0] = __builtin_amdgcn_mfma_f32_16x16x32_bf16(af0, bf0, acc[0][0], 0, 0, 0);
    acc[0][1] = __builtin_amdgcn_mfma_f32_16x16x32_bf16(af0, bf1, acc[0][1], 0, 0, 0);
    acc[1][0] = __builtin_amdgcn_mfma_f32_16x16x32_bf16(af1, bf0, acc[1][0], 0, 0, 0);
    acc[1][1] = __builtin_amdgcn_mfma_f32_16x16x32_bf16(af1, bf1, acc[1][1], 0, 0, 0);
    __syncthreads();
  }
#pragma unroll
  for (int tm = 0; tm < 2; ++tm)
#pragma unroll
    for (int tn = 0; tn < 2; ++tn) {
      int col = n0 + wn * 32 + tn * 16 + (lane & 15);
      float bv = bias[col];
#pragma unroll
      for (int r = 0; r < 4; ++r) {
        int row = row0 + wm * 32 + tm * 16 + ((lane >> 4) * 4) + r;
        if (row < M)
          C[(size_t)row * N + col] = acc[tm][tn][r] + bv;
      }
    }
}

// ---------------- GRU recurrence body (R9-proven; encoder variant) -----------
template<int XPT>
__device__ void gru_body(char* smem, const float* __restrict__ U,
                         const float* __restrict__ xp, const float* __restrict__ br,
                         unsigned short* __restrict__ hpub,
                         unsigned int* __restrict__ flags) {
  unsigned short* ub = (unsigned short*)smem;                   // 48 KiB
  char* hbase = smem + 49152;                                   // 32 KiB
  float (*recbuf)[32][16] = (float (*)[32][16])(smem + 81920);  // 6 KiB
  int tid = threadIdx.x;
  int lane = tid & 63;
  int w = tid >> 6;
  int g = blockIdx.x;

  for (int idx = tid; idx < 16 * 3 * 64 * 8; idx += 512) {
    int i = idx & 7;
    int l = (idx >> 3) & 63;
    int rem = idx >> 9;
    int nt = rem % 3;
    int ks = rem / 3;
    int k = ks * 32 + ((l >> 4) * 8) + i;
    int col = nt * 512 + g * 16 + (l & 15);
    ub[idx] = f2bf(U[(size_t)k * G3 + col]);
  }
  int b = tid >> 4, j = tid & 15;
  float br_z = br[g * 16 + j];
  float br_r = br[512 + g * 16 + j];
  float br_h = br[1024 + g * 16 + j];
  float hreg = 0.f;
  __syncthreads();

  int mt = w / 3, nt = w % 3;
  for (int t = 0; t < TT; ++t) {
    size_t xbase = ((size_t)(t * XPT + b)) * G3 + g * 16 + j;
    float xz = xp[xbase], xr = xp[xbase + 512], xh = xp[xbase + 1024];

    float rz, rr, rh;
    if (t == 0) {
      rz = 0.f; rr = 0.f; rh = 0.f;
    } else {
      {
        const unsigned long long* hr =
            (const unsigned long long*)(hpub + ((t & 1) ? 16384 : 0));
        int r = tid >> 4, s = tid & 15;
        unsigned long long av[8];
#pragma unroll
        for (int k = 0; k < 4; ++k) {
          const unsigned long long* p = hr + (size_t)r * 128 + (s + 16 * k) * 2;
          av[2 * k] = AL64(p);
          av[2 * k + 1] = AL64(p + 1);
        }
        int rx = (r & 7) << 4;
#pragma unroll
        for (int k = 0; k < 4; ++k) {
          int wb = (r * 1024 + (s + 16 * k) * 16) ^ rx;
          u64x2 v;
          v[0] = av[2 * k];
          v[1] = av[2 * k + 1];
          *(u64x2*)(hbase + wb) = v;
        }
      }
      __syncthreads();

      if (w < 6) {
        int arow = mt * 16 + (lane & 15);
        int rx = (arow & 7) << 4;
        int abase = arow * 1024 + (lane >> 4) * 16;
        f32x4 acc0 = (f32x4){0.f, 0.f, 0.f, 0.f};
        f32x4 acc1 = (f32x4){0.f, 0.f, 0.f, 0.f};
#pragma unroll
        for (int ks = 0; ks < 8; ++ks) {
          short8 af0 = *(const short8*)(hbase + ((abase + ks * 64) ^ rx));
          short8 af1 = *(const short8*)(hbase + ((abase + (ks + 8) * 64) ^ rx));
          short8 bf0 = *(const short8*)&ub[((ks * 3 + nt) * 64 + lane) * 8];
          short8 bf1 = *(const short8*)&ub[(((ks + 8) * 3 + nt) * 64 + lane) * 8];
          acc0 = __builtin_amdgcn_mfma_f32_16x16x32_bf16(af0, bf0, acc0, 0, 0, 0);
          acc1 = __builtin_amdgcn_mfma_f32_16x16x32_bf16(af1, bf1, acc1, 0, 0, 0);
        }
        f32x4 acc = acc0 + acc1;
#pragma unroll
        for (int r = 0; r < 4; ++r)
          recbuf[nt][mt * 16 + (lane >> 4) * 4 + r][lane & 15] = acc[r];
      }
      __syncthreads();
      rz = recbuf[0][b][j];
      rr = recbuf[1][b][j];
      rh = recbuf[2][b][j];
    }

    float z = 1.f / (1.f + __expf(-(xz + rz + br_z)));
    float rg = 1.f / (1.f + __expf(-(xr + rr + br_r)));
    float pre = xh + rg * (rh + br_h);
    pre = fminf(fmaxf(pre, -15.f), 15.f);
    float e2 = __expf(2.f * pre);
    float hh = (e2 - 1.f) / (e2 + 1.f);
    hreg = z * hreg + (1.f - z) * hh;
    unsigned short hb = f2bf(hreg);

    unsigned int hv = (unsigned int)hb;
    unsigned int p1 = (unsigned int)__shfl_xor((int)hv, 1, 64);
    unsigned long long lo = (unsigned long long)((hv & 0xffffu) | (p1 << 16));
    unsigned long long hi =
        (unsigned long long)(unsigned int)__shfl_xor((int)(unsigned int)lo, 2, 64);
    if ((j & 3) == 0) {
      unsigned long long pk = (lo & 0xffffffffull) | (hi << 32);
      AS64((unsigned long long*)(hpub + (((t + 1) & 1) ? 16384 : 0) +
                                 b * HID + g * 16 + j), pk);
    }

    if (t + 1 < TT) {
      asm volatile("s_waitcnt vmcnt(0)" ::: "memory");  // publish stores done
      __syncthreads();
      if (tid == 0)
        AS32(flags + g * 32, (unsigned)(t + 1));
      if (lane < 32) {
        const unsigned int* fp = flags + lane * 32;
        while (AL32(fp) < (unsigned)(t + 1)) {}
      }
    }
  }
}

// ---------------- standalone decoder GRU (R9-proven, WRITE_ALL) --------------
__launch_bounds__(512)
__global__ void gru_k(const float* __restrict__ U,
                      const float* __restrict__ xp,
                      const float* __restrict__ br,
                      unsigned short* __restrict__ hpub,   // 2 x 32 x 512 bf16
                      unsigned short* __restrict__ hsout,  // [b*TT+t][512]
                      unsigned int* __restrict__ flags) {  // 32 flags, stride 32
  __shared__ unsigned short ub[16 * 3 * 64 * 8];   // 48 KiB
  __shared__ unsigned short hbuf[16384];           // 32 KiB
  __shared__ float recbuf[3][32][16];              // 6 KiB
  int tid = threadIdx.x;
  int lane = tid & 63;
  int w = tid >> 6;
  int g = blockIdx.x;
  char* hbase = (char*)hbuf;

  for (int idx = tid; idx < 16 * 3 * 64 * 8; idx += 512) {
    int i = idx & 7;
    int l = (idx >> 3) & 63;
    int rem = idx >> 9;
    int nt = rem % 3;
    int ks = rem / 3;
    int k = ks * 32 + ((l >> 4) * 8) + i;
    int col = nt * 512 + g * 16 + (l & 15);
    ub[idx] = f2bf(U[(size_t)k * G3 + col]);
  }
  int b = tid >> 4, j = tid & 15;
  float br_z = br[g * 16 + j];
  float br_r = br[512 + g * 16 + j];
  float br_h = br[1024 + g * 16 + j];
  float hreg = 0.f;
  __syncthreads();

  int mt = w / 3, nt = w % 3;
  for (int t = 0; t < TT; ++t) {
    size_t xbase = ((size_t)b) * G3 + g * 16 + j;   // XPT=0: same xp every step
    float xz = xp[xbase], xr = xp[xbase + 512], xh = xp[xbase + 1024];

    float rz, rr, rh;
    if (t == 0) {
      rz = 0.f; rr = 0.f; rh = 0.f;
    } else {
      {
        const unsigned long long* hr =
            (const unsigned long long*)(hpub + ((t & 1) ? 16384 : 0));
        int r = tid >> 4, s = tid & 15;
        unsigned long long av[8];
#pragma unroll
        for (int k = 0; k < 4; ++k) {
          const unsigned long long* p = hr + (size_t)r * 128 + (s + 16 * k) * 2;
          av[2 * k] = AL64(p);
          av[2 * k + 1] = AL64(p + 1);
        }
        int rx = (r & 7) << 4;
#pragma unroll
        for (int k = 0; k < 4; ++k) {
          int wb = (r * 1024 + (s + 16 * k) * 16) ^ rx;
          u64x2 v;
          v[0] = av[2 * k];
          v[1] = av[2 * k + 1];
          *(u64x2*)(hbase + wb) = v;
        }
      }
      __syncthreads();

      if (w < 6) {
        int arow = mt * 16 + (lane & 15);
        int rx = (arow & 7) << 4;
        int abase = arow * 1024 + (lane >> 4) * 16;
        f32x4 acc0 = (f32x4){0.f, 0.f, 0.f, 0.f};
        f32x4 acc1 = (f32x4){0.f, 0.f, 0.f, 0.f};
#pragma unroll
        for (int ks = 0; ks < 8; ++ks) {
          short8 af0 = *(const short8*)(hbase + ((abase + ks * 64) ^ rx));
          short8 af1 = *(const short8*)(hbase + ((abase + (ks + 8) * 64) ^ rx));
          short8 bf0 = *(const short8*)&ub[((ks * 3 + nt) * 64 + lane) * 8];
          short8 bf1 = *(const short8*)&ub[(((ks + 8) * 3 + nt) * 64 + lane) * 8];
          acc0 = __builtin_amdgcn_mfma_f32_16x16x32_bf16(af0, bf0, acc0, 0, 0, 0);
          acc1 = __builtin_amdgcn_mfma_f32_16x16x32_bf16(af1, bf1, acc1, 0, 0, 0);
        }
        f32x4 acc = acc0 + acc1;
#pragma unroll
        for (int r = 0; r < 4; ++r)
          recbuf[nt][mt * 16 + (lane >> 4) * 4 + r][lane & 15] = acc[r];
      }
      __syncthreads();
      rz = recbuf[0][b][j];
      rr = recbuf[1][b][j];
      rh = recbuf[2][b][j];
    }

    float z = 1.f / (1.f + __expf(-(xz + rz + br_z)));
    float rg = 1.f / (1.f + __expf(-(xr + rr + br_r)));
    float pre = xh + rg * (rh + br_h);
    pre = fminf(fmaxf(pre, -15.f), 15.f);
    float e2 = __expf(2.f * pre);
    float hh = (e2 - 1.f) / (e2 + 1.f);
    hreg = z * hreg + (1.f - z) * hh;
    unsigned short hb = f2bf(hreg);

    unsigned int hv = (unsigned int)hb;
    unsigned int p1 = (unsigned int)__shfl_xor((int)hv, 1, 64);
    unsigned long long lo = (unsigned long long)((hv & 0xffffu) | (p1 << 16));
    unsigned long long hi =
        (unsigned long long)(unsigned int)__shfl_xor((int)(unsigned int)lo, 2, 64);
    if ((j & 3) == 0) {
      unsigned long long pk = (lo & 0xffffffffull) | (hi << 32);
      AS64((unsigned long long*)(hpub + (((t + 1) & 1) ? 16384 : 0) +
                                 b * HID + g * 16 + j), pk);
    }

    if (t + 1 < TT) {
      asm volatile("s_waitcnt vmcnt(0)" ::: "memory");
      __syncthreads();
      if (tid == 0)
        AS32(flags + g * 32, (unsigned)(t + 1));
    }
    // HBM hs store drains during the poll, off the ack path
    hsout[((size_t)b * TT + t) * HID + g * 16 + j] = hb;
    if (t + 1 < TT) {
      if (lane < 32) {
        const unsigned int* fp = flags + lane * 32;
        while (AL32(fp) < (unsigned)(t + 1)) {}
      }
    }
  }
}

// ---------------- aux transpose tile (256 threads, 1 barrier) ----------------
__device__ void tr_tile(char* sm, int tid8, const float* __restrict__ src,
                        unsigned short* __restrict__ dst,
                        int K, int N, int k0, int n0) {
  float (*t)[65] = (float (*)[65])sm;   // 64x65 f32 = 16640 B
  int c = tid8 & 15, rr = tid8 >> 4;
#pragma unroll
  for (int i = 0; i < 4; ++i) {
    float4 v = *(const float4*)(src + (size_t)(k0 + rr + 16 * i) * N + n0 + c * 4);
    t[rr + 16 * i][c * 4 + 0] = v.x;
    t[rr + 16 * i][c * 4 + 1] = v.y;
    t[rr + 16 * i][c * 4 + 2] = v.z;
    t[rr + 16 * i][c * 4 + 3] = v.w;
  }
  __syncthreads();
#pragma unroll
  for (int i = 0; i < 4; ++i) {
    short4v o;
#pragma unroll
    for (int j = 0; j < 4; ++j) o[j] = (short)f2bf(t[c * 4 + j][rr + 16 * i]);
    *(short4v*)(dst + (size_t)(n0 + rr + 16 * i) * K + k0 + c * 4) = o;
  }
}

// ---------------- dispatch A: encoder GRU + aux preprocessing ----------------
__launch_bounds__(512)
__global__ void enc_fused_k(const float* __restrict__ U,
                            const float* __restrict__ xp,
                            const float* __restrict__ br,
                            unsigned short* __restrict__ hpub,
                            unsigned int* __restrict__ flags,
                            const float* __restrict__ w_out,
                            unsigned short* __restrict__ woutbT,
                            const float* __restrict__ w_relu,
                            unsigned short* __restrict__ wrelubT,
                            const float* __restrict__ decW,
                            unsigned short* __restrict__ decWb) {
  __shared__ char smem[88064];
  if (blockIdx.x < 32) {
    gru_body<32>(smem, U, xp, br, hpub, flags);
    return;
  }
  int tid = threadIdx.x;
  int wid = (int)blockIdx.x - 32;
  int eng = tid >> 8, tid8 = tid & 255;
  char* sm = smem + eng * 36864;
  for (int it = 0; it < 10; ++it) {          // ceil(4448/448)=10
    int tk = wid * 2 + eng + it * 448;
    if (tk < 4000) {
      tr_tile(sm, tid8, w_out, woutbT, 512, VOCAB, (tk & 7) * 64, (tk >> 3) * 64);
    } else if (tk < 4064) {
      int t2 = tk - 4000;
      tr_tile(sm, tid8, w_relu, wrelubT, 512, 512, (t2 & 7) * 64, (t2 >> 3) * 64);
    } else if (tk < 4448) {
      int c = tk - 4064;                     // 384 chunks x 2048 f32
      int base = c * 2048 + tid8 * 8;
      float4 a = *(const float4*)(decW + base);
      float4 bq = *(const float4*)(decW + base + 4);
      short8 o;
      o[0] = (short)f2bf(a.x); o[1] = (short)f2bf(a.y);
      o[2] = (short)f2bf(a.z); o[3] = (short)f2bf(a.w);
      o[4] = (short)f2bf(bq.x); o[5] = (short)f2bf(bq.y);
      o[6] = (short)f2bf(bq.z); o[7] = (short)f2bf(bq.w);
      *(short8*)(decWb + base) = o;
      __syncthreads();                       // match tr_tile barrier count
    } else {
      __syncthreads();
    }
  }
}

// ---------------- softmax denominator + normalize ----------------------------
__global__ void rowsum_k(const float* __restrict__ part, float* __restrict__ inv) {
  int r = blockIdx.x * blockDim.x + threadIdx.x;   // 4096
  float s = 0.f;
  for (int c = 0; c < NCB; ++c) s += part[(size_t)c * NROW + r];
  inv[r] = 1.f / s;
}

__global__ void norm2_k(const unsigned short* __restrict__ lg,
                        const float* __restrict__ inv,
                        float* __restrict__ out) {
  const unsigned int C8 = VOCAB / 8;
  const unsigned int total8 = (unsigned int)NROW * C8;
  unsigned int stride = gridDim.x * blockDim.x;
  for (unsigned int i = blockIdx.x * blockDim.x + threadIdx.x; i < total8;
       i += stride) {
    unsigned int r = i / C8;                 // const divisor -> magic mul
    float s = inv[r];
    short8 v = __builtin_nontemporal_load((const short8*)(lg + (size_t)i * 8));
    f32x4 a, b;
    a[0] = __expf(bf2f((unsigned short)v[0])) * s;
    a[1] = __expf(bf2f((unsigned short)v[1])) * s;
    a[2] = __expf(bf2f((unsigned short)v[2])) * s;
    a[3] = __expf(bf2f((unsigned short)v[3])) * s;
    b[0] = __expf(bf2f((unsigned short)v[4])) * s;
    b[1] = __expf(bf2f((unsigned short)v[5])) * s;
    b[2] = __expf(bf2f((unsigned short)v[6])) * s;
    b[3] = __expf(bf2f((unsigned short)v[7])) * s;
    __builtin_nontemporal_store(a, (f32x4*)(out + (size_t)i * 8));
    __builtin_nontemporal_store(b, (f32x4*)(out + (size_t)i * 8 + 4));
  }
}

// ---------------- launch -----------------------------------------------------
extern "C" void kernel_launch(void* const* d_in, const int* in_sizes, int n_in,
                              void* d_out, int out_size, void* d_ws, size_t ws_size,
                              hipStream_t stream) {
  const int*   inputs = (const int*)d_in[0];
  const float* emb    = (const float*)d_in[1];
  const float* encW   = (const float*)d_in[2];
  const float* encU   = (const float*)d_in[3];
  const float* enc_bi = (const float*)d_in[4];
  const float* enc_br = (const float*)d_in[5];
  const float* decW   = (const float*)d_in[6];
  const float* decU   = (const float*)d_in[7];
  const float* dec_bi = (const float*)d_in[8];
  const float* dec_br = (const float*)d_in[9];
  const float* w_relu = (const float*)d_in[10];
  const float* b_relu = (const float*)d_in[11];
  const float* w_out  = (const float*)d_in[12];
  const float* b_out  = (const float*)d_in[13];

  char* ws = (char*)d_ws;
  const size_t o_xproj  = 0;                        // 25165824
  const size_t o_xb     = 25165824;                 // 4194304
  const size_t o_encWbT = 29360128;                 // 1572864
  const size_t o_decWb  = 30932992;                 // 1572864
  const size_t o_wrelubT= 32505856;                 // 524288
  const size_t o_woutbT = 33030144;                 // 32768000
  const size_t o_decxp  = 65798144;                 // 196608
  const size_t o_hsb    = 65994752;                 // 4194304 ([b*TT+t][512] bf16)
  const size_t o_h1b    = 70189056;                 // 4194304
  const size_t o_part   = 74383360;                 // 8192000 (flags early, partials late)
  const size_t o_inv    = 82575360;                 // 16384
  const size_t o_hpubE  = 82591744;                 // 65536
  const size_t o_hpubD  = 82657280;                 // 65536
  const size_t o_logit  = 82722816;                 // 262144000

  float*          xproj   = (float*)(ws + o_xproj);
  unsigned short* xb      = (unsigned short*)(ws + o_xb);
  unsigned short* encWbT  = (unsigned short*)(ws + o_encWbT);
  unsigned short* decWb   = (unsigned short*)(ws + o_decWb);
  unsigned short* wrelubT = (unsigned short*)(ws + o_wrelubT);
  unsigned short* woutbT  = (unsigned short*)(ws + o_woutbT);
  float*          decxp   = (float*)(ws + o_decxp);
  unsigned short* hsb     = (unsigned short*)(ws + o_hsb);
  unsigned short* h1b     = (unsigned short*)(ws + o_h1b);
  float*          part    = (float*)(ws + o_part);
  float*          inv     = (float*)(ws + o_inv);
  unsigned short* hpubE   = (unsigned short*)(ws + o_hpubE);
  unsigned short* hpubD   = (unsigned short*)(ws + o_hpubD);
  unsigned short* logit   = (unsigned short*)(ws + o_logit);
  unsigned int*   flagsE  = (unsigned int*)(ws + o_part);          // 4 KiB
  unsigned int*   flagsD  = (unsigned int*)(ws + o_part + 4096);   // 4 KiB
  // flags alias `part`: consumed inside GRU dispatches, before gemm partials.

  // zero flags only (hpub double-buffers are fully written before any read)
  (void)hipMemsetAsync(ws + o_part, 0, 8192, stream);

  // encW transpose (needed by xproj GEMM immediately) — standalone
  transpose_bf16_k<<<dim3(8, 24), 256, 0, stream>>>(encW, encWbT, HID, G3);
  embed_k<<<4096, 128, 0, stream>>>(inputs, emb, xb);

  // encoder input projection: [4096,512] @ W^T + bi
  gemm_bt<0><<<dim3(32, 12), 256, 0, stream>>>(xb, encWbT, enc_bi, xproj,
                                               nullptr, NROW, G3, HID);

  // dispatch A: encoder GRU (32 blocks) + aux preprocessing (224 blocks)
  enc_fused_k<<<256, 512, 0, stream>>>(encU, xproj, enc_br, hpubE, flagsE,
                                       w_out, woutbT, w_relu, wrelubT,
                                       decW, decWb);

  // decoder input projection (reads final h from hpubE parity 0)
  gemm_small_k<<<dim3(1, 24), 256, 0, stream>>>(hpubE, decWb, dec_bi, decxp,
                                                BB, G3, HID);

  // decoder GRU (standalone, R9 protocol), hs -> [b*TT+t][512]
  gru_k<<<32, 512, 0, stream>>>(decU, decxp, dec_br, hpubD, hsb, flagsD);

  // h1 = relu(hs @ w_relu + b_relu), bf16
  gemm_bt<1><<<dim3(32, 4), 256, 0, stream>>>(hsb, wrelubT, b_relu, h1b,
                                              nullptr, NROW, HID, HID);
  // bf16 logits (non-temporal) + per-row exp partials
  gemm_bt<3><<<dim3(32, NCB), 256, 0, stream>>>(h1b, woutbT, b_out, logit,
                                                part, NROW, VOCAB, HID);
  rowsum_k<<<16, 256, 0, stream>>>(part, inv);
  norm2_k<<<2048, 256, 0, stream>>>(logit, inv, (float*)d_out);
}

// Round 17
// 1260.101 us; speedup vs baseline: 1.0537x; 1.0537x over previous
//
#include <hip/hip_runtime.h>
#include <stdint.h>

#define VOCAB 32000
#define HID   512
#define G3    1536
#define TT    128
#define BB    32
#define NROW  4096   // TT*BB rows
#define NCB   250    // VOCAB/128 column blocks of the vocab GEMM

typedef __attribute__((ext_vector_type(8))) short short8;
typedef __attribute__((ext_vector_type(4))) short short4v;
typedef __attribute__((ext_vector_type(4))) float f32x4;
typedef __attribute__((ext_vector_type(2))) unsigned long long u64x2;

__device__ __forceinline__ unsigned short f2bf(float f) {
  unsigned int u = __builtin_bit_cast(unsigned int, f);
  u += 0x7fffu + ((u >> 16) & 1u);
  return (unsigned short)(u >> 16);
}
__device__ __forceinline__ float bf2f(unsigned short s) {
  unsigned int u = ((unsigned int)s) << 16;
  return __builtin_bit_cast(float, u);
}
__device__ __forceinline__ void gload16(const void* g, void* l) {
  __builtin_amdgcn_global_load_lds(
      (const __attribute__((address_space(1))) unsigned int*)g,
      (__attribute__((address_space(3))) unsigned int*)l, 16, 0, 0);
}
__device__ __forceinline__ unsigned long long AL64(const unsigned long long* p) {
  return __hip_atomic_load(p, __ATOMIC_RELAXED, __HIP_MEMORY_SCOPE_AGENT);
}
__device__ __forceinline__ unsigned int AL32(const unsigned int* p) {
  return __hip_atomic_load(p, __ATOMIC_RELAXED, __HIP_MEMORY_SCOPE_AGENT);
}
__device__ __forceinline__ void AS64(unsigned long long* p, unsigned long long v) {
  __hip_atomic_store(p, v, __ATOMIC_RELAXED, __HIP_MEMORY_SCOPE_AGENT);
}
__device__ __forceinline__ void AS32(unsigned int* p, unsigned int v) {
  __hip_atomic_store(p, v, __ATOMIC_RELAXED, __HIP_MEMORY_SCOPE_AGENT);
}

// ---------------- f32 [K][N] -> bf16 [N][K] transpose (standalone, encW) -----
__global__ void transpose_bf16_k(const float* __restrict__ src,
                                 unsigned short* __restrict__ dst,
                                 int K, int N) {
  __shared__ float t[64][65];
  int k0 = blockIdx.x * 64, n0 = blockIdx.y * 64;
  int c = threadIdx.x & 15, rr = threadIdx.x >> 4;
#pragma unroll
  for (int i = 0; i < 4; ++i) {
    float4 v = *(const float4*)(src + (size_t)(k0 + rr + 16 * i) * N + n0 + c * 4);
    t[rr + 16 * i][c * 4 + 0] = v.x;
    t[rr + 16 * i][c * 4 + 1] = v.y;
    t[rr + 16 * i][c * 4 + 2] = v.z;
    t[rr + 16 * i][c * 4 + 3] = v.w;
  }
  __syncthreads();
#pragma unroll
  for (int i = 0; i < 4; ++i) {
    short4v o;
#pragma unroll
    for (int j = 0; j < 4; ++j) o[j] = (short)f2bf(t[c * 4 + j][rr + 16 * i]);
    *(short4v*)(dst + (size_t)(n0 + rr + 16 * i) * K + k0 + c * 4) = o;
  }
}

// ---------------- embedding gather -------------------------------------------
__global__ void embed_k(const int* __restrict__ inputs,
                        const float* __restrict__ emb,
                        unsigned short* __restrict__ xb) {
  int r = blockIdx.x;            // r = t*32 + b
  int t = r >> 5, b = r & 31;
  int idx = inputs[b * TT + t];
  const float* src = emb + (size_t)idx * HID;
  unsigned short* dst = xb + (size_t)r * HID;
  int j = threadIdx.x * 4;
  float4 v = *(const float4*)(src + j);
  short4v o;
  o[0] = (short)f2bf(v.x); o[1] = (short)f2bf(v.y);
  o[2] = (short)f2bf(v.z); o[3] = (short)f2bf(v.w);
  *(short4v*)(dst + j) = o;
}

// ---------------- B^T MFMA GEMM, 128x128 tile, BK=64, global_load_lds --------
// XCD-aware block swizzle (grid.x MUST be 32, total blocks % 8 == 0).
// MODE 0: C=f32 +bias. MODE 1: C=bf16 relu(+bias).
// MODE 3: C=bf16 raw logit(+bias) + per-row partial sums of exp (f32 acc).
template<int MODE>
__launch_bounds__(256)
__global__ void gemm_bt(const unsigned short* __restrict__ A,
                        const unsigned short* __restrict__ BT,
                        const float* __restrict__ bias,
                        void* __restrict__ Cv,
                        float* __restrict__ partials,
                        int M, int N, int K) {
  __shared__ unsigned short As[8192];   // 128 rows x 64 k, swizzled, 16 KiB
  __shared__ unsigned short Bs[8192];   // 128 cols x 64 k, swizzled, 16 KiB
  __shared__ float rsum[2][128];
  int tid = threadIdx.x;
  int l = tid & 63;
  int w = tid >> 6;
  int wm = w >> 1, wn = w & 1;

  int nwg = (int)(gridDim.x * gridDim.y);
  int id = (int)(blockIdx.y * gridDim.x + blockIdx.x);
  int nid = (id & 7) * (nwg >> 3) + (id >> 3);
  int bx = nid & 31, by = nid >> 5;     // gridDim.x == 32 by construction
  int row0 = bx * 128;
  int col0 = by * 128;

  int sr = (w << 5) + (l >> 3);                 // + i*8, i=0..3
  int sg = ((l & 7) ^ ((l >> 3) & 7)) << 3;     // short offset in k-window
  const unsigned short* Ag = A  + (size_t)(row0 + sr) * K + sg;
  const unsigned short* Bg = BT + (size_t)(col0 + sr) * K + sg;

  int cA = l & 15, q = l >> 4, x7 = l & 7;
  const char* asp = (const char*)As;
  const char* bsp = (const char*)Bs;

  f32x4 acc[4][4];
#pragma unroll
  for (int m = 0; m < 4; ++m)
#pragma unroll
    for (int n = 0; n < 4; ++n) acc[m][n] = (f32x4){0.f, 0.f, 0.f, 0.f};

  for (int k0 = 0; k0 < K; k0 += 64) {
    if (k0) __syncthreads();               // previous-tile reads complete
#pragma unroll
    for (int i = 0; i < 4; ++i) {
      gload16(Ag + (size_t)(i * 8) * K + k0, As + ((w << 2) + i) * 512);
      gload16(Bg + (size_t)(i * 8) * K + k0, Bs + ((w << 2) + i) * 512);
    }
    __syncthreads();                       // loads landed (vmcnt drained)
#pragma unroll
    for (int kk = 0; kk < 2; ++kk) {
      int sl = (((kk << 2) + q) ^ x7) << 4;   // swizzled 16B slot in row
      short8 af[4], bf[4];
#pragma unroll
      for (int m = 0; m < 4; ++m)
        af[m] = *(const short8*)(asp + (wm * 64 + m * 16 + cA) * 128 + sl);
#pragma unroll
      for (int n = 0; n < 4; ++n)
        bf[n] = *(const short8*)(bsp + (wn * 64 + n * 16 + cA) * 128 + sl);
#pragma unroll
      for (int m = 0; m < 4; ++m)
#pragma unroll
        for (int n = 0; n < 4; ++n)
          acc[m][n] = __builtin_amdgcn_mfma_f32_16x16x32_bf16(af[m], bf[n],
                                                              acc[m][n], 0, 0, 0);
    }
  }

  if (MODE == 0 || MODE == 1) {
#pragma unroll
    for (int m = 0; m < 4; ++m)
#pragma unroll
      for (int n = 0; n < 4; ++n) {
        int col = col0 + wn * 64 + n * 16 + cA;
        float bv = bias[col];
#pragma unroll
        for (int r = 0; r < 4; ++r) {
          int row = row0 + wm * 64 + m * 16 + q * 4 + r;
          float v = acc[m][n][r] + bv;
          if (MODE == 0)
            ((float*)Cv)[(size_t)row * N + col] = v;
          else
            ((unsigned short*)Cv)[(size_t)row * N + col] = f2bf(fmaxf(v, 0.f));
        }
      }
  } else {
    float ps[4][4];
#pragma unroll
    for (int m = 0; m < 4; ++m)
#pragma unroll
      for (int r = 0; r < 4; ++r) ps[m][r] = 0.f;
#pragma unroll
    for (int m = 0; m < 4; ++m)
#pragma unroll
      for (int n = 0; n < 4; ++n) {
        int col = col0 + wn * 64 + n * 16 + cA;
        float bv = bias[col];
#pragma unroll
        for (int r = 0; r < 4; ++r) {
          int row = row0 + wm * 64 + m * 16 + q * 4 + r;
          float lv = acc[m][n][r] + bv;
          float v = __expf(lv);
          ((unsigned short*)Cv)[(size_t)row * N + col] = f2bf(lv);
          ps[m][r] += v;
        }
      }
#pragma unroll
    for (int mask = 1; mask < 16; mask <<= 1)
#pragma unroll
      for (int m = 0; m < 4; ++m)
#pragma unroll
        for (int r = 0; r < 4; ++r)
          ps[m][r] += __shfl_xor(ps[m][r], mask, 64);
    if (cA == 0) {
#pragma unroll
      for (int m = 0; m < 4; ++m)
#pragma unroll
        for (int r = 0; r < 4; ++r)
          rsum[wn][wm * 64 + m * 16 + q * 4 + r] = ps[m][r];
    }
    __syncthreads();
    if (tid < 128)
      partials[(size_t)by * NROW + row0 + tid] = rsum[0][tid] + rsum[1][tid];
  }
}

// ---------------- small GEMM (decoder input projection only) -----------------
__launch_bounds__(256)
__global__ void gemm_small_k(const unsigned short* __restrict__ A,
                             const unsigned short* __restrict__ B,
                             const float* __restrict__ bias,
                             float* __restrict__ C,
                             int M, int N, int K) {
  __shared__ unsigned short As[64][56];
  __shared__ unsigned short Bs[64][56];
  int tid = threadIdx.x;
  int lane = tid & 63;
  int w = tid >> 6;
  int wm = w >> 1, wn = w & 1;
  int row0 = blockIdx.x * 64;
  int n0 = blockIdx.y * 64;
  f32x4 acc[2][2];
#pragma unroll
  for (int a = 0; a < 2; ++a)
#pragma unroll
    for (int c = 0; c < 2; ++c) acc[a][c] = (f32x4){0.f, 0.f, 0.f, 0.f};
  for (int k0 = 0; k0 < K; k0 += 32) {
    {
      int row = tid >> 2;
      int kg = (tid & 3) * 8;
      short8 v = {};
      if (row0 + row < M)
        v = *(const short8*)(A + (size_t)(row0 + row) * K + k0 + kg);
      *(short8*)&As[row][kg] = v;
    }
    {
      int k = tid >> 3;
      int ng = (tid & 7) * 8;
      short8 v = *(const short8*)(B + (size_t)(k0 + k) * N + n0 + ng);
#pragma unroll
      for (int qq = 0; qq < 8; ++qq) Bs[ng + qq][k] = (unsigned short)v[qq];
    }
    __syncthreads();
    int kb = (lane >> 4) * 8;
    short8 af0 = *(const short8*)&As[wm * 32 + (lane & 15)][kb];
    short8 af1 = *(const short8*)&As[wm * 32 + 16 + (lane & 15)][kb];
    short8 bf0 = *(const short8*)&Bs[wn * 32 + (lane & 15)][kb];
    short8 bf1 = *(const short8*)&Bs[wn * 32 + 16 + (lane & 15)][kb];
    acc[0][0] = __builtin_amdgcn_mfma_f32_16x16x32_bf16(af0, bf0, acc[0][0], 0, 0, 0);
    acc[0][1] = __builtin_amdgcn_mfma_f32_16x16x32_bf16(af0, bf1, acc[0][1], 0, 0, 0);
    acc[1][0] = __builtin_amdgcn_mfma_f32_16x16x32_bf16(af1, bf0, acc[1][0], 0, 0, 0);
    acc[1][1] = __builtin_amdgcn_mfma_f32_16x16x32_bf16(af1, bf1, acc[1][1], 0, 0, 0);
    __syncthreads();
  }
#pragma unroll
  for (int tm = 0; tm < 2; ++tm)
#pragma unroll
    for (int tn = 0; tn < 2; ++tn) {
      int col = n0 + wn * 32 + tn * 16 + (lane & 15);
      float bv = bias[col];
#pragma unroll
      for (int r = 0; r < 4; ++r) {
        int row = row0 + wm * 32 + tm * 16 + ((lane >> 4) * 4) + r;
        if (row < M)
          C[(size_t)row * N + col] = acc[tm][tn][r] + bv;
      }
    }
}

// ---------------- GRU recurrence body (R9-proven; encoder variant) -----------
template<int XPT>
__device__ void gru_body(char* smem, const float* __restrict__ U,
                         const float* __restrict__ xp, const float* __restrict__ br,
                         unsigned short* __restrict__ hpub,
                         unsigned int* __restrict__ flags) {
  unsigned short* ub = (unsigned short*)smem;                   // 48 KiB
  char* hbase = smem + 49152;                                   // 32 KiB
  float (*recbuf)[32][16] = (float (*)[32][16])(smem + 81920);  // 6 KiB
  int tid = threadIdx.x;
  int lane = tid & 63;
  int w = tid >> 6;
  int g = blockIdx.x;

  for (int idx = tid; idx < 16 * 3 * 64 * 8; idx += 512) {
    int i = idx & 7;
    int l = (idx >> 3) & 63;
    int rem = idx >> 9;
    int nt = rem % 3;
    int ks = rem / 3;
    int k = ks * 32 + ((l >> 4) * 8) + i;
    int col = nt * 512 + g * 16 + (l & 15);
    ub[idx] = f2bf(U[(size_t)k * G3 + col]);
  }
  int b = tid >> 4, j = tid & 15;
  float br_z = br[g * 16 + j];
  float br_r = br[512 + g * 16 + j];
  float br_h = br[1024 + g * 16 + j];
  float hreg = 0.f;
  __syncthreads();

  int mt = w / 3, nt = w % 3;
  for (int t = 0; t < TT; ++t) {
    size_t xbase = ((size_t)(t * XPT + b)) * G3 + g * 16 + j;
    float xz = xp[xbase], xr = xp[xbase + 512], xh = xp[xbase + 1024];

    float rz, rr, rh;
    if (t == 0) {
      rz = 0.f; rr = 0.f; rh = 0.f;
    } else {
      {
        const unsigned long long* hr =
            (const unsigned long long*)(hpub + ((t & 1) ? 16384 : 0));
        int r = tid >> 4, s = tid & 15;
        unsigned long long av[8];
#pragma unroll
        for (int k = 0; k < 4; ++k) {
          const unsigned long long* p = hr + (size_t)r * 128 + (s + 16 * k) * 2;
          av[2 * k] = AL64(p);
          av[2 * k + 1] = AL64(p + 1);
        }
        int rx = (r & 7) << 4;
#pragma unroll
        for (int k = 0; k < 4; ++k) {
          int wb = (r * 1024 + (s + 16 * k) * 16) ^ rx;
          u64x2 v;
          v[0] = av[2 * k];
          v[1] = av[2 * k + 1];
          *(u64x2*)(hbase + wb) = v;
        }
      }
      __syncthreads();

      if (w < 6) {
        int arow = mt * 16 + (lane & 15);
        int rx = (arow & 7) << 4;
        int abase = arow * 1024 + (lane >> 4) * 16;
        f32x4 acc0 = (f32x4){0.f, 0.f, 0.f, 0.f};
        f32x4 acc1 = (f32x4){0.f, 0.f, 0.f, 0.f};
#pragma unroll
        for (int ks = 0; ks < 8; ++ks) {
          short8 af0 = *(const short8*)(hbase + ((abase + ks * 64) ^ rx));
          short8 af1 = *(const short8*)(hbase + ((abase + (ks + 8) * 64) ^ rx));
          short8 bf0 = *(const short8*)&ub[((ks * 3 + nt) * 64 + lane) * 8];
          short8 bf1 = *(const short8*)&ub[(((ks + 8) * 3 + nt) * 64 + lane) * 8];
          acc0 = __builtin_amdgcn_mfma_f32_16x16x32_bf16(af0, bf0, acc0, 0, 0, 0);
          acc1 = __builtin_amdgcn_mfma_f32_16x16x32_bf16(af1, bf1, acc1, 0, 0, 0);
        }
        f32x4 acc = acc0 + acc1;
#pragma unroll
        for (int r = 0; r < 4; ++r)
          recbuf[nt][mt * 16 + (lane >> 4) * 4 + r][lane & 15] = acc[r];
      }
      __syncthreads();
      rz = recbuf[0][b][j];
      rr = recbuf[1][b][j];
      rh = recbuf[2][b][j];
    }

    float z = 1.f / (1.f + __expf(-(xz + rz + br_z)));
    float rg = 1.f / (1.f + __expf(-(xr + rr + br_r)));
    float pre = xh + rg * (rh + br_h);
    pre = fminf(fmaxf(pre, -15.f), 15.f);
    float e2 = __expf(2.f * pre);
    float hh = (e2 - 1.f) / (e2 + 1.f);
    hreg = z * hreg + (1.f - z) * hh;
    unsigned short hb = f2bf(hreg);

    unsigned int hv = (unsigned int)hb;
    unsigned int p1 = (unsigned int)__shfl_xor((int)hv, 1, 64);
    unsigned long long lo = (unsigned long long)((hv & 0xffffu) | (p1 << 16));
    unsigned long long hi =
        (unsigned long long)(unsigned int)__shfl_xor((int)(unsigned int)lo, 2, 64);
    if ((j & 3) == 0) {
      unsigned long long pk = (lo & 0xffffffffull) | (hi << 32);
      AS64((unsigned long long*)(hpub + (((t + 1) & 1) ? 16384 : 0) +
                                 b * HID + g * 16 + j), pk);
    }

    if (t + 1 < TT) {
      asm volatile("s_waitcnt vmcnt(0)" ::: "memory");  // publish stores done
      __syncthreads();
      if (tid == 0)
        AS32(flags + g * 32, (unsigned)(t + 1));
      if (lane < 32) {
        const unsigned int* fp = flags + lane * 32;
        while (AL32(fp) < (unsigned)(t + 1)) {}
      }
    }
  }
}

// ---------------- standalone decoder GRU (R9-proven, WRITE_ALL) --------------
__launch_bounds__(512)
__global__ void gru_k(const float* __restrict__ U,
                      const float* __restrict__ xp,
                      const float* __restrict__ br,
                      unsigned short* __restrict__ hpub,   // 2 x 32 x 512 bf16
                      unsigned short* __restrict__ hsout,  // [b*TT+t][512]
                      unsigned int* __restrict__ flags) {  // 32 flags, stride 32
  __shared__ unsigned short ub[16 * 3 * 64 * 8];   // 48 KiB
  __shared__ unsigned short hbuf[16384];           // 32 KiB
  __shared__ float recbuf[3][32][16];              // 6 KiB
  int tid = threadIdx.x;
  int lane = tid & 63;
  int w = tid >> 6;
  int g = blockIdx.x;
  char* hbase = (char*)hbuf;

  for (int idx = tid; idx < 16 * 3 * 64 * 8; idx += 512) {
    int i = idx & 7;
    int l = (idx >> 3) & 63;
    int rem = idx >> 9;
    int nt = rem % 3;
    int ks = rem / 3;
    int k = ks * 32 + ((l >> 4) * 8) + i;
    int col = nt * 512 + g * 16 + (l & 15);
    ub[idx] = f2bf(U[(size_t)k * G3 + col]);
  }
  int b = tid >> 4, j = tid & 15;
  float br_z = br[g * 16 + j];
  float br_r = br[512 + g * 16 + j];
  float br_h = br[1024 + g * 16 + j];
  float hreg = 0.f;
  __syncthreads();

  int mt = w / 3, nt = w % 3;
  for (int t = 0; t < TT; ++t) {
    size_t xbase = ((size_t)b) * G3 + g * 16 + j;   // XPT=0: same xp every step
    float xz = xp[xbase], xr = xp[xbase + 512], xh = xp[xbase + 1024];

    float rz, rr, rh;
    if (t == 0) {
      rz = 0.f; rr = 0.f; rh = 0.f;
    } else {
      {
        const unsigned long long* hr =
            (const unsigned long long*)(hpub + ((t & 1) ? 16384 : 0));
        int r = tid >> 4, s = tid & 15;
        unsigned long long av[8];
#pragma unroll
        for (int k = 0; k < 4; ++k) {
          const unsigned long long* p = hr + (size_t)r * 128 + (s + 16 * k) * 2;
          av[2 * k] = AL64(p);
          av[2 * k + 1] = AL64(p + 1);
        }
        int rx = (r & 7) << 4;
#pragma unroll
        for (int k = 0; k < 4; ++k) {
          int wb = (r * 1024 + (s + 16 * k) * 16) ^ rx;
          u64x2 v;
          v[0] = av[2 * k];
          v[1] = av[2 * k + 1];
          *(u64x2*)(hbase + wb) = v;
        }
      }
      __syncthreads();

      if (w < 6) {
        int arow = mt * 16 + (lane & 15);
        int rx = (arow & 7) << 4;
        int abase = arow * 1024 + (lane >> 4) * 16;
        f32x4 acc0 = (f32x4){0.f, 0.f, 0.f, 0.f};
        f32x4 acc1 = (f32x4){0.f, 0.f, 0.f, 0.f};
#pragma unroll
        for (int ks = 0; ks < 8; ++ks) {
          short8 af0 = *(const short8*)(hbase + ((abase + ks * 64) ^ rx));
          short8 af1 = *(const short8*)(hbase + ((abase + (ks + 8) * 64) ^ rx));
          short8 bf0 = *(const short8*)&ub[((ks * 3 + nt) * 64 + lane) * 8];
          short8 bf1 = *(const short8*)&ub[(((ks + 8) * 3 + nt) * 64 + lane) * 8];
          acc0 = __builtin_amdgcn_mfma_f32_16x16x32_bf16(af0, bf0, acc0, 0, 0, 0);
          acc1 = __builtin_amdgcn_mfma_f32_16x16x32_bf16(af1, bf1, acc1, 0, 0, 0);
        }
        f32x4 acc = acc0 + acc1;
#pragma unroll
        for (int r = 0; r < 4; ++r)
          recbuf[nt][mt * 16 + (lane >> 4) * 4 + r][lane & 15] = acc[r];
      }
      __syncthreads();
      rz = recbuf[0][b][j];
      rr = recbuf[1][b][j];
      rh = recbuf[2][b][j];
    }

    float z = 1.f / (1.f + __expf(-(xz + rz + br_z)));
    float rg = 1.f / (1.f + __expf(-(xr + rr + br_r)));
    float pre = xh + rg * (rh + br_h);
    pre = fminf(fmaxf(pre, -15.f), 15.f);
    float e2 = __expf(2.f * pre);
    float hh = (e2 - 1.f) / (e2 + 1.f);
    hreg = z * hreg + (1.f - z) * hh;
    unsigned short hb = f2bf(hreg);

    unsigned int hv = (unsigned int)hb;
    unsigned int p1 = (unsigned int)__shfl_xor((int)hv, 1, 64);
    unsigned long long lo = (unsigned long long)((hv & 0xffffu) | (p1 << 16));
    unsigned long long hi =
        (unsigned long long)(unsigned int)__shfl_xor((int)(unsigned int)lo, 2, 64);
    if ((j & 3) == 0) {
      unsigned long long pk = (lo & 0xffffffffull) | (hi << 32);
      AS64((unsigned long long*)(hpub + (((t + 1) & 1) ? 16384 : 0) +
                                 b * HID + g * 16 + j), pk);
    }

    if (t + 1 < TT) {
      asm volatile("s_waitcnt vmcnt(0)" ::: "memory");
      __syncthreads();
      if (tid == 0)
        AS32(flags + g * 32, (unsigned)(t + 1));
    }
    // HBM hs store drains during the poll, off the ack path
    hsout[((size_t)b * TT + t) * HID + g * 16 + j] = hb;
    if (t + 1 < TT) {
      if (lane < 32) {
        const unsigned int* fp = flags + lane * 32;
        while (AL32(fp) < (unsigned)(t + 1)) {}
      }
    }
  }
}

// ---------------- aux transpose tile (256 threads, 1 barrier) ----------------
__device__ void tr_tile(char* sm, int tid8, const float* __restrict__ src,
                        unsigned short* __restrict__ dst,
                        int K, int N, int k0, int n0) {
  float (*t)[65] = (float (*)[65])sm;   // 64x65 f32 = 16640 B
  int c = tid8 & 15, rr = tid8 >> 4;
#pragma unroll
  for (int i = 0; i < 4; ++i) {
    float4 v = *(const float4*)(src + (size_t)(k0 + rr + 16 * i) * N + n0 + c * 4);
    t[rr + 16 * i][c * 4 + 0] = v.x;
    t[rr + 16 * i][c * 4 + 1] = v.y;
    t[rr + 16 * i][c * 4 + 2] = v.z;
    t[rr + 16 * i][c * 4 + 3] = v.w;
  }
  __syncthreads();
#pragma unroll
  for (int i = 0; i < 4; ++i) {
    short4v o;
#pragma unroll
    for (int j = 0; j < 4; ++j) o[j] = (short)f2bf(t[c * 4 + j][rr + 16 * i]);
    *(short4v*)(dst + (size_t)(n0 + rr + 16 * i) * K + k0 + c * 4) = o;
  }
}

// ---------------- dispatch A: encoder GRU + aux preprocessing ----------------
__launch_bounds__(512)
__global__ void enc_fused_k(const float* __restrict__ U,
                            const float* __restrict__ xp,
                            const float* __restrict__ br,
                            unsigned short* __restrict__ hpub,
                            unsigned int* __restrict__ flags,
                            const float* __restrict__ w_out,
                            unsigned short* __restrict__ woutbT,
                            const float* __restrict__ w_relu,
                            unsigned short* __restrict__ wrelubT,
                            const float* __restrict__ decW,
                            unsigned short* __restrict__ decWb) {
  __shared__ char smem[88064];
  if (blockIdx.x < 32) {
    gru_body<32>(smem, U, xp, br, hpub, flags);
    return;
  }
  int tid = threadIdx.x;
  int wid = (int)blockIdx.x - 32;
  int eng = tid >> 8, tid8 = tid & 255;
  char* sm = smem + eng * 36864;
  for (int it = 0; it < 10; ++it) {          // ceil(4448/448)=10
    int tk = wid * 2 + eng + it * 448;
    if (tk < 4000) {
      tr_tile(sm, tid8, w_out, woutbT, 512, VOCAB, (tk & 7) * 64, (tk >> 3) * 64);
    } else if (tk < 4064) {
      int t2 = tk - 4000;
      tr_tile(sm, tid8, w_relu, wrelubT, 512, 512, (t2 & 7) * 64, (t2 >> 3) * 64);
    } else if (tk < 4448) {
      int c = tk - 4064;                     // 384 chunks x 2048 f32
      int base = c * 2048 + tid8 * 8;
      float4 a = *(const float4*)(decW + base);
      float4 bq = *(const float4*)(decW + base + 4);
      short8 o;
      o[0] = (short)f2bf(a.x); o[1] = (short)f2bf(a.y);
      o[2] = (short)f2bf(a.z); o[3] = (short)f2bf(a.w);
      o[4] = (short)f2bf(bq.x); o[5] = (short)f2bf(bq.y);
      o[6] = (short)f2bf(bq.z); o[7] = (short)f2bf(bq.w);
      *(short8*)(decWb + base) = o;
      __syncthreads();                       // match tr_tile barrier count
    } else {
      __syncthreads();
    }
  }
}

// ---------------- softmax denominator + normalize ----------------------------
__global__ void rowsum_k(const float* __restrict__ part, float* __restrict__ inv) {
  int r = blockIdx.x * blockDim.x + threadIdx.x;   // 4096
  float s = 0.f;
  for (int c = 0; c < NCB; ++c) s += part[(size_t)c * NROW + r];
  inv[r] = 1.f / s;
}

__global__ void norm2_k(const unsigned short* __restrict__ lg,
                        const float* __restrict__ inv,
                        float* __restrict__ out) {
  const unsigned int C8 = VOCAB / 8;
  const unsigned int total8 = (unsigned int)NROW * C8;
  unsigned int stride = gridDim.x * blockDim.x;
  for (unsigned int i = blockIdx.x * blockDim.x + threadIdx.x; i < total8;
       i += stride) {
    unsigned int r = i / C8;                 // const divisor -> magic mul
    float s = inv[r];
    short8 v = *(const short8*)(lg + (size_t)i * 8);
    float4 a, b;
    a.x = __expf(bf2f((unsigned short)v[0])) * s;
    a.y = __expf(bf2f((unsigned short)v[1])) * s;
    a.z = __expf(bf2f((unsigned short)v[2])) * s;
    a.w = __expf(bf2f((unsigned short)v[3])) * s;
    b.x = __expf(bf2f((unsigned short)v[4])) * s;
    b.y = __expf(bf2f((unsigned short)v[5])) * s;
    b.z = __expf(bf2f((unsigned short)v[6])) * s;
    b.w = __expf(bf2f((unsigned short)v[7])) * s;
    *(float4*)(out + (size_t)i * 8) = a;
    *(float4*)(out + (size_t)i * 8 + 4) = b;
  }
}

// ---------------- launch -----------------------------------------------------
extern "C" void kernel_launch(void* const* d_in, const int* in_sizes, int n_in,
                              void* d_out, int out_size, void* d_ws, size_t ws_size,
                              hipStream_t stream) {
  const int*   inputs = (const int*)d_in[0];
  const float* emb    = (const float*)d_in[1];
  const float* encW   = (const float*)d_in[2];
  const float* encU   = (const float*)d_in[3];
  const float* enc_bi = (const float*)d_in[4];
  const float* enc_br = (const float*)d_in[5];
  const float* decW   = (const float*)d_in[6];
  const float* decU   = (const float*)d_in[7];
  const float* dec_bi = (const float*)d_in[8];
  const float* dec_br = (const float*)d_in[9];
  const float* w_relu = (const float*)d_in[10];
  const float* b_relu = (const float*)d_in[11];
  const float* w_out  = (const float*)d_in[12];
  const float* b_out  = (const float*)d_in[13];

  char* ws = (char*)d_ws;
  const size_t o_xproj  = 0;                        // 25165824
  const size_t o_xb     = 25165824;                 // 4194304
  const size_t o_encWbT = 29360128;                 // 1572864
  const size_t o_decWb  = 30932992;                 // 1572864
  const size_t o_wrelubT= 32505856;                 // 524288
  const size_t o_woutbT = 33030144;                 // 32768000
  const size_t o_decxp  = 65798144;                 // 196608
  const size_t o_hsb    = 65994752;                 // 4194304 ([b*TT+t][512] bf16)
  const size_t o_h1b    = 70189056;                 // 4194304
  const size_t o_part   = 74383360;                 // 8192000 (flags early, partials late)
  const size_t o_inv    = 82575360;                 // 16384
  const size_t o_hpubE  = 82591744;                 // 65536
  const size_t o_hpubD  = 82657280;                 // 65536
  const size_t o_logit  = 82722816;                 // 262144000

  float*          xproj   = (float*)(ws + o_xproj);
  unsigned short* xb      = (unsigned short*)(ws + o_xb);
  unsigned short* encWbT  = (unsigned short*)(ws + o_encWbT);
  unsigned short* decWb   = (unsigned short*)(ws + o_decWb);
  unsigned short* wrelubT = (unsigned short*)(ws + o_wrelubT);
  unsigned short* woutbT  = (unsigned short*)(ws + o_woutbT);
  float*          decxp   = (float*)(ws + o_decxp);
  unsigned short* hsb     = (unsigned short*)(ws + o_hsb);
  unsigned short* h1b     = (unsigned short*)(ws + o_h1b);
  float*          part    = (float*)(ws + o_part);
  float*          inv     = (float*)(ws + o_inv);
  unsigned short* hpubE   = (unsigned short*)(ws + o_hpubE);
  unsigned short* hpubD   = (unsigned short*)(ws + o_hpubD);
  unsigned short* logit   = (unsigned short*)(ws + o_logit);
  unsigned int*   flagsE  = (unsigned int*)(ws + o_part);          // 4 KiB
  unsigned int*   flagsD  = (unsigned int*)(ws + o_part + 4096);   // 4 KiB
  // flags alias `part`: consumed inside GRU dispatches, before gemm partials.

  // zero flags only (hpub double-buffers are fully written before any read:
  // step t reads parity t&1 which step t-1 fully wrote; gemm_small reads
  // parity 0, fully written at t=127)
  (void)hipMemsetAsync(ws + o_part, 0, 8192, stream);

  // encW transpose (needed by xproj GEMM immediately) — standalone
  transpose_bf16_k<<<dim3(8, 24), 256, 0, stream>>>(encW, encWbT, HID, G3);
  embed_k<<<4096, 128, 0, stream>>>(inputs, emb, xb);

  // encoder input projection: [4096,512] @ W^T + bi
  gemm_bt<0><<<dim3(32, 12), 256, 0, stream>>>(xb, encWbT, enc_bi, xproj,
                                               nullptr, NROW, G3, HID);

  // dispatch A: encoder GRU (32 blocks) + aux preprocessing (224 blocks)
  enc_fused_k<<<256, 512, 0, stream>>>(encU, xproj, enc_br, hpubE, flagsE,
                                       w_out, woutbT, w_relu, wrelubT,
                                       decW, decWb);

  // decoder input projection (reads final h from hpubE parity 0)
  gemm_small_k<<<dim3(1, 24), 256, 0, stream>>>(hpubE, decWb, dec_bi, decxp,
                                                BB, G3, HID);

  // decoder GRU (standalone, R9 protocol), hs -> [b*TT+t][512]
  gru_k<<<32, 512, 0, stream>>>(decU, decxp, dec_br, hpubD, hsb, flagsD);

  // h1 = relu(hs @ w_relu + b_relu), bf16
  gemm_bt<1><<<dim3(32, 4), 256, 0, stream>>>(hsb, wrelubT, b_relu, h1b,
                                              nullptr, NROW, HID, HID);
  // bf16 logits + per-row exp partials
  gemm_bt<3><<<dim3(32, NCB), 256, 0, stream>>>(h1b, woutbT, b_out, logit,
                                                part, NROW, VOCAB, HID);
  rowsum_k<<<16, 256, 0, stream>>>(part, inv);
  norm2_k<<<2048, 256, 0, stream>>>(logit, inv, (float*)d_out);
}